// Round 1
// baseline (232.819 us; speedup 1.0000x reference)
//
#include <hip/hip_runtime.h>
#include <hip/hip_bf16.h>

// VectorQuantize: B=16, D=256, T=4096, K=1024.
// Pipeline:
//   prep    : W -> fp16 (scaled x1024), swizzled tile layout in ws; zero counts/loss.
//   stageA  : S = X * W^T via mfma_f32_16x16x32_f16; per-lane top-2 packed (val|idx),
//             cross-lane merge -> top-4 candidates per row -> ws.
//   stageBC : fp64-exact distance of 4 candidates -> winner; counts atomics, loss sum,
//             writes out[b][d][t] = w[winner][d].
//   finalize: vq_loss and perplexity scalars.
// ws usage: 512KB (w16) + 1MB (cand) + 4KB (counts) + 8B (loss) ~= 1.58 MB.

#define DD   256
#define KK   1024
#define TT   4096
#define BBB  16
#define NROW (BBB*TT)          // 65536

typedef _Float16 half8 __attribute__((ext_vector_type(8)));
typedef float f32x4 __attribute__((ext_vector_type(4)));

__device__ __forceinline__ unsigned umaxu(unsigned a, unsigned b) { return a > b ? a : b; }
__device__ __forceinline__ unsigned uminu(unsigned a, unsigned b) { return a < b ? a : b; }

// ---------------- prep: convert+scale W to fp16 in swizzled tile layout ----------------
// Layout: tile (64 codes) major; within tile: code kc has 32 chunks of 8 halves,
// chunk c stored at slot (c ^ (kc&31)) for bank-balanced b128 access.
__global__ void prep(const float* __restrict__ w, _Float16* __restrict__ w16,
                     unsigned* __restrict__ counts, double* __restrict__ lsum) {
    int gid = blockIdx.x * 256 + threadIdx.x;      // 0..32767
    int k = gid >> 5;                              // code 0..1023
    int c = gid & 31;                              // d-chunk of 8
    int tile = k >> 6, kc = k & 63;
    const float* src = w + (k << 8) + (c << 3);
    union { uint4 u; _Float16 h[8]; } pk;
#pragma unroll
    for (int j = 0; j < 8; ++j) pk.h[j] = (_Float16)(src[j] * 1024.0f);
    int swz = c ^ (kc & 31);
    *(uint4*)(w16 + ((size_t)tile << 14) + (kc << 8) + (swz << 3)) = pk.u;
    if (gid < KK) counts[gid] = 0u;
    if (gid == KK) *lsum = 0.0;
}

// ---------------- stage A: scores + top-4 candidates per row ----------------
// 256 blocks x 512 threads. Block owns 256 rows (one b, 256 consecutive t).
// Wave wv owns rows [wv*32, wv*32+32) = two 16-row m-tiles. A-frags in registers.
__global__ __launch_bounds__(512) void stageA(const float* __restrict__ x,
                                              const _Float16* __restrict__ w16,
                                              uint4* __restrict__ cand) {
    __shared__ __align__(16) _Float16 sbuf[64 * 256];   // 32 KB X staging (64 rows)
    __shared__ __align__(16) _Float16 wt[64 * 256];     // 32 KB W tile (64 codes)
    int tid = threadIdx.x;
    int bid = blockIdx.x;
    int b  = bid >> 4;
    int t0 = (bid & 15) << 8;
    const float* xbase = x + ((size_t)b << 20) + t0;    // b*D*T

    int lane = tid & 63;
    int wv = tid >> 6;          // wave 0..7
    int n = lane & 15;
    int q = lane >> 4;

    half8 afrag[2][8];

    // Stage X rows in 4 groups of 64 rows through sbuf; owning waves grab A-frags.
    for (int g = 0; g < 4; ++g) {
        int rl = tid & 63;
        int cg = tid >> 6;           // 0..7
#pragma unroll
        for (int it = 0; it < 4; ++it) {
            int c = cg * 4 + it;     // d-chunk 0..31
            const float* gsrc = xbase + ((size_t)(c << 3) << 12) + (g << 6) + rl;
            union { uint4 u; _Float16 h[8]; } pk;
#pragma unroll
            for (int j = 0; j < 8; ++j) pk.h[j] = (_Float16)gsrc[(size_t)j << 12];
            *(uint4*)(&sbuf[(rl << 8) + ((c ^ (rl & 31)) << 3)]) = pk.u;
        }
        __syncthreads();
        if ((wv >> 1) == g) {
            int wloc = wv & 1;
#pragma unroll
            for (int mt = 0; mt < 2; ++mt) {
                int row = wloc * 32 + mt * 16 + n;   // local row in sbuf
#pragma unroll
                for (int ks = 0; ks < 8; ++ks) {
                    int c = ks * 4 + q;
                    afrag[mt][ks] = *(const half8*)(&sbuf[(row << 8) + ((c ^ (row & 31)) << 3)]);
                }
            }
        }
        __syncthreads();
    }

    unsigned b1[8], b2[8];
#pragma unroll
    for (int i = 0; i < 8; ++i) { b1[i] = 0u; b2[i] = 0u; }

    for (int wti = 0; wti < 16; ++wti) {
        __syncthreads();   // protect previous tile reads
        const uint4* wsrc = (const uint4*)(w16 + ((size_t)wti << 14));
#pragma unroll
        for (int it = 0; it < 4; ++it)
            ((uint4*)wt)[(it << 9) + tid] = wsrc[(it << 9) + tid];
        __syncthreads();

        for (int ct = 0; ct < 4; ++ct) {
            int kc = (ct << 4) + n;          // local code 0..63
            half8 bfr[8];
#pragma unroll
            for (int ks = 0; ks < 8; ++ks)
                bfr[ks] = *(const half8*)(&wt[(kc << 8) + (((ks * 4 + q) ^ (kc & 31)) << 3)]);
            f32x4 a0 = {0.f, 0.f, 0.f, 0.f};
            f32x4 a1 = {0.f, 0.f, 0.f, 0.f};
#pragma unroll
            for (int ks = 0; ks < 8; ++ks) {
                a0 = __builtin_amdgcn_mfma_f32_16x16x32_f16(afrag[0][ks], bfr[ks], a0, 0, 0, 0);
                a1 = __builtin_amdgcn_mfma_f32_16x16x32_f16(afrag[1][ks], bfr[ks], a1, 0, 0, 0);
            }
            unsigned kg = (unsigned)((wti << 6) + kc);
#pragma unroll
            for (int i = 0; i < 4; ++i) {
                float v = fmaxf(a0[i], 0.0f);
                unsigned p = (__float_as_uint(v) & 0xFFFFFC00u) | kg;
                unsigned o = b1[i];
                b2[i] = umaxu(b2[i], uminu(p, o));
                b1[i] = umaxu(o, p);
                v = fmaxf(a1[i], 0.0f);
                p = (__float_as_uint(v) & 0xFFFFFC00u) | kg;
                o = b1[4 + i];
                b2[4 + i] = umaxu(b2[4 + i], uminu(p, o));
                b1[4 + i] = umaxu(o, p);
            }
        }
    }

    // Cross-lane merge: top-4 of the 16 column-lanes' top-2 lists, per row.
#pragma unroll
    for (int s = 0; s < 8; ++s) {
        unsigned v0 = b1[s], v1 = b2[s], v2 = 0u, v3 = 0u;
#pragma unroll
        for (int m = 1; m <= 8; m <<= 1) {
            unsigned e0 = __shfl_xor(v0, m);
            unsigned e1 = __shfl_xor(v1, m);
            unsigned e2 = __shfl_xor(v2, m);
            unsigned e3 = __shfl_xor(v3, m);
#pragma unroll
            for (int u = 0; u < 4; ++u) {
                unsigned e = (u == 0) ? e0 : (u == 1) ? e1 : (u == 2) ? e2 : e3;
                unsigned t;
                t = umaxu(e, v0); e = uminu(e, v0); v0 = t;
                t = umaxu(e, v1); e = uminu(e, v1); v1 = t;
                t = umaxu(e, v2); e = uminu(e, v2); v2 = t;
                v3 = umaxu(e, v3);
            }
        }
        if (n == 0) {
            int row = (bid << 8) + (wv << 5) + ((s >> 2) << 4) + (q << 2) + (s & 3);
            cand[row] = make_uint4(v0, v1, v2, v3);
        }
    }
}

// ---------------- stage B+C: fp64 refine, loss, counts, output ----------------
// 1024 blocks x 256 threads. Block owns 64 rows (one b, 64 consecutive t).
__global__ __launch_bounds__(256) void stageBC(const float* __restrict__ x,
                                               const float* __restrict__ w,
                                               const unsigned* __restrict__ cand,
                                               float* __restrict__ out,
                                               unsigned* __restrict__ counts,
                                               double* __restrict__ lsum) {
    __shared__ int winner[64];
    __shared__ double ldis[64];
    int tid = threadIdx.x, bid = blockIdx.x;
    int b = bid >> 6, t0 = (bid & 63) << 6;
    int r = tid >> 2, j = tid & 3;
    int rowg = (b << 12) + t0 + r;
    unsigned pk = cand[(size_t)rowg * 4 + j];
    int ci = (int)(pk & 1023u);
    const float* xcol = x + ((size_t)b << 20) + t0 + r;
    const float* wrow = w + (ci << 8);
    double s0 = 0.0, s1 = 0.0, s2 = 0.0, s3 = 0.0;
#pragma unroll 4
    for (int d4 = 0; d4 < 64; ++d4) {
        float4 wv4 = ((const float4*)wrow)[d4];
        int dbase = d4 << 2;
        double e0 = (double)xcol[(size_t)(dbase + 0) << 12] - (double)wv4.x;
        double e1 = (double)xcol[(size_t)(dbase + 1) << 12] - (double)wv4.y;
        double e2 = (double)xcol[(size_t)(dbase + 2) << 12] - (double)wv4.z;
        double e3 = (double)xcol[(size_t)(dbase + 3) << 12] - (double)wv4.w;
        s0 = fma(e0, e0, s0); s1 = fma(e1, e1, s1);
        s2 = fma(e2, e2, s2); s3 = fma(e3, e3, s3);
    }
    double dis = (s0 + s1) + (s2 + s3);
#pragma unroll
    for (int m = 1; m <= 2; m <<= 1) {
        double od = __shfl_xor(dis, m);
        int oc = __shfl_xor(ci, m);
        if (od < dis || (od == dis && oc < ci)) { dis = od; ci = oc; }
    }
    if (j == 0) {
        winner[r] = ci;
        ldis[r] = dis;
        atomicAdd(&counts[ci], 1u);
    }
    __syncthreads();
    if (tid < 32) ldis[tid] += ldis[tid + 32];
    __syncthreads();
    if (tid < 16) ldis[tid] += ldis[tid + 16];
    __syncthreads();
    if (tid < 8) ldis[tid] += ldis[tid + 8];
    __syncthreads();
    if (tid < 4) ldis[tid] += ldis[tid + 4];
    __syncthreads();
    if (tid < 2) ldis[tid] += ldis[tid + 2];
    __syncthreads();
    if (tid == 0) atomicAdd(lsum, ldis[0] + ldis[1]);

    // phase 3: out[b][d][t] = w[winner[t]][d]
    int t = tid & 63;
    int dbb = tid >> 6;            // 0..3
    int win = winner[t];
    const float* wr = w + (win << 8);
    float* ob = out + ((size_t)b << 20) + t0 + t;
#pragma unroll 4
    for (int it = 0; it < 64; ++it) {
        int d = dbb + (it << 2);
        ob[(size_t)d << 12] = wr[d];
    }
}

// ---------------- finalize: scalars ----------------
__global__ void finalize(const unsigned* __restrict__ counts,
                         const double* __restrict__ lsum,
                         float* __restrict__ out2) {
    __shared__ double part[256];
    int tid = threadIdx.x;
    double s = 0.0;
    for (int i = tid; i < KK; i += 256) {
        double p = (double)counts[i] / (double)NROW;
        s += p * log(p + 1e-10);
    }
    part[tid] = s;
    __syncthreads();
    for (int st = 128; st > 0; st >>= 1) {
        if (tid < st) part[tid] += part[tid + st];
        __syncthreads();
    }
    if (tid == 0) {
        out2[0] = (float)(1.25 * (*lsum) / ((double)NROW * (double)DD));
        out2[1] = (float)exp(-part[0]);
    }
}

extern "C" void kernel_launch(void* const* d_in, const int* in_sizes, int n_in,
                              void* d_out, int out_size, void* d_ws, size_t ws_size,
                              hipStream_t stream) {
    const float* x = (const float*)d_in[0];
    const float* w = (const float*)d_in[1];
    float* out = (float*)d_out;
    char* ws = (char*)d_ws;
    _Float16* w16   = (_Float16*)ws;                                    // 524288 B
    uint4*    cnd   = (uint4*)(ws + 524288);                            // 1 MB
    unsigned* counts = (unsigned*)(ws + 524288 + 1048576);              // 4 KB
    double*   lsum   = (double*)(ws + 524288 + 1048576 + 4096);         // 8 B

    prep<<<128, 256, 0, stream>>>(w, w16, counts, lsum);
    stageA<<<256, 512, 0, stream>>>(x, w16, cnd);
    stageBC<<<1024, 256, 0, stream>>>(x, w, (const unsigned*)cnd, out, counts, lsum);
    finalize<<<1, 256, 0, stream>>>(counts, lsum, out + (size_t)NROW * DD);
}

// Round 2
// 208.522 us; speedup vs baseline: 1.1165x; 1.1165x over previous
//
#include <hip/hip_runtime.h>
#include <hip/hip_bf16.h>

// VectorQuantize: B=16, D=256, T=4096, K=1024.
//   prep    : W -> fp16 (x1024, swizzled tiles) + wsq[k]=512*||w_k||^2; zero counts/loss.
//   stageA  : scores via mfma_f32_16x16x32_f16, rank by s - 512||e||^2, per-lane top-2,
//             cross-lane merge -> top-4 candidates/row. 512 blocks x 256 thr, 128 rows/blk,
//             A-frags direct from global (no x LDS staging), LDS = 36KB.
//   stageBC : LDS-staged x tile (coalesced), fp64 refine with d-spanning-lane coalesced
//             w reads, winner/counts/loss, LDS-staged w gather -> coalesced float4 out.
//   finalize: vq_loss + perplexity.

#define DD   256
#define KK   1024
#define TT   4096
#define BBB  16
#define NROW (BBB*TT)

typedef _Float16 half8 __attribute__((ext_vector_type(8)));
typedef float f32x4 __attribute__((ext_vector_type(4)));

__device__ __forceinline__ unsigned umaxu(unsigned a, unsigned b) { return a > b ? a : b; }
__device__ __forceinline__ unsigned uminu(unsigned a, unsigned b) { return a < b ? a : b; }

// ---------------- prep ----------------
__global__ void prep(const float* __restrict__ w, _Float16* __restrict__ w16,
                     unsigned* __restrict__ counts, double* __restrict__ lsum,
                     float* __restrict__ wsq) {
    int gid = blockIdx.x * 256 + threadIdx.x;      // 0..32767
    int k = gid >> 5;                              // code 0..1023
    int c = gid & 31;                              // d-chunk of 8
    int tile = k >> 6, kc = k & 63;
    const float* src = w + (k << 8) + (c << 3);
    union { uint4 u; _Float16 h[8]; } pk;
#pragma unroll
    for (int j = 0; j < 8; ++j) pk.h[j] = (_Float16)(src[j] * 1024.0f);
    int swz = c ^ (kc & 31);
    *(uint4*)(w16 + ((size_t)tile << 14) + (kc << 8) + (swz << 3)) = pk.u;
    if (c == 0) {
        const float4* wr4 = (const float4*)(w + (k << 8));
        float s = 0.f;
#pragma unroll 8
        for (int ii = 0; ii < 64; ++ii) {
            float4 v = wr4[ii];
            s += v.x * v.x + v.y * v.y + v.z * v.z + v.w * v.w;
        }
        wsq[k] = 512.0f * s;
    }
    if (gid < KK) counts[gid] = 0u;
    if (gid == KK) *lsum = 0.0;
}

// ---------------- stage A ----------------
// 512 blocks x 256 threads (4 waves). Block owns 128 rows (one b, 128 consecutive t).
// Wave wv owns rows [wv*32, wv*32+32) = two 16-row m-tiles; A-frags from global directly.
__global__ __launch_bounds__(256) void stageA(const float* __restrict__ x,
                                              const _Float16* __restrict__ w16,
                                              const float* __restrict__ wsq,
                                              uint4* __restrict__ cand) {
    __shared__ __align__(16) _Float16 wt[64 * 256];   // 32 KB W tile
    __shared__ __align__(16) float wsql[KK];          // 4 KB
    int tid = threadIdx.x, bid = blockIdx.x;
    int b = bid >> 5;
    int t0 = (bid & 31) << 7;
    const float* xbase = x + ((size_t)b << 20) + t0;

    int lane = tid & 63, wv = tid >> 6;
    int n = lane & 15, q = lane >> 4;

    ((float4*)wsql)[tid] = ((const float4*)wsq)[tid];

    // A fragments: rows wv*32 + mt*16 + n, k-elements d = ks*32 + q*8 + j
    half8 afrag[2][8];
#pragma unroll
    for (int mt = 0; mt < 2; ++mt) {
        int rl = (wv << 5) + (mt << 4) + n;
#pragma unroll
        for (int ks = 0; ks < 8; ++ks) {
            const float* p = xbase + (((size_t)((ks << 5) + (q << 3))) << 12) + rl;
            half8 f;
#pragma unroll
            for (int j = 0; j < 8; ++j) f[j] = (_Float16)p[(size_t)j << 12];
            afrag[mt][ks] = f;
        }
    }

    unsigned b1[8], b2[8];
#pragma unroll
    for (int i = 0; i < 8; ++i) { b1[i] = 0u; b2[i] = 0u; }

    for (int wti = 0; wti < 16; ++wti) {
        __syncthreads();
        const uint4* wsrc = (const uint4*)(w16 + ((size_t)wti << 14));
#pragma unroll
        for (int it = 0; it < 8; ++it)
            ((uint4*)wt)[(it << 8) + tid] = wsrc[(it << 8) + tid];
        __syncthreads();

#pragma unroll
        for (int ct = 0; ct < 4; ++ct) {
            int kc = (ct << 4) + n;
            float csub = wsql[(wti << 6) + kc];
            half8 bfr[8];
#pragma unroll
            for (int ks = 0; ks < 8; ++ks)
                bfr[ks] = *(const half8*)(&wt[(kc << 8) + ((((ks << 2) + q) ^ (kc & 31)) << 3)]);
            f32x4 a0 = {0.f, 0.f, 0.f, 0.f};
            f32x4 a1 = {0.f, 0.f, 0.f, 0.f};
#pragma unroll
            for (int ks = 0; ks < 8; ++ks) {
                a0 = __builtin_amdgcn_mfma_f32_16x16x32_f16(afrag[0][ks], bfr[ks], a0, 0, 0, 0);
                a1 = __builtin_amdgcn_mfma_f32_16x16x32_f16(afrag[1][ks], bfr[ks], a1, 0, 0, 0);
            }
            unsigned kg = (unsigned)((wti << 6) + kc);
#pragma unroll
            for (int i = 0; i < 4; ++i) {
                float v = fmaxf(a0[i] - csub, 0.0f);
                unsigned p = (__float_as_uint(v) & 0xFFFFFC00u) | kg;
                unsigned o = b1[i];
                b2[i] = umaxu(b2[i], uminu(p, o));
                b1[i] = umaxu(o, p);
                v = fmaxf(a1[i] - csub, 0.0f);
                p = (__float_as_uint(v) & 0xFFFFFC00u) | kg;
                o = b1[4 + i];
                b2[4 + i] = umaxu(b2[4 + i], uminu(p, o));
                b1[4 + i] = umaxu(o, p);
            }
        }
    }

    // merge the 16 column-lanes' top-2 -> per-row top-4
#pragma unroll
    for (int s = 0; s < 8; ++s) {
        unsigned v0 = b1[s], v1 = b2[s], v2 = 0u, v3 = 0u;
#pragma unroll
        for (int m = 1; m <= 8; m <<= 1) {
            unsigned e0 = __shfl_xor(v0, m);
            unsigned e1 = __shfl_xor(v1, m);
            unsigned e2 = __shfl_xor(v2, m);
            unsigned e3 = __shfl_xor(v3, m);
#pragma unroll
            for (int u = 0; u < 4; ++u) {
                unsigned e = (u == 0) ? e0 : (u == 1) ? e1 : (u == 2) ? e2 : e3;
                unsigned t;
                t = umaxu(e, v0); e = uminu(e, v0); v0 = t;
                t = umaxu(e, v1); e = uminu(e, v1); v1 = t;
                t = umaxu(e, v2); e = uminu(e, v2); v2 = t;
                v3 = umaxu(e, v3);
            }
        }
        if (n == 0) {
            int row_local = (wv << 5) + ((s >> 2) << 4) + (q << 2) + (s & 3);
            cand[(bid << 7) + row_local] = make_uint4(v0, v1, v2, v3);
        }
    }
}

// ---------------- stage B+C ----------------
// 1024 blocks x 256 threads (4 waves). Block owns 64 rows (one b, 64 consecutive t).
#define XLS 260   // padded row stride (floats), multiple of 4
__global__ __launch_bounds__(256) void stageBC(const float* __restrict__ x,
                                               const float* __restrict__ w,
                                               const uint4* __restrict__ cand,
                                               float* __restrict__ out,
                                               unsigned* __restrict__ counts,
                                               double* __restrict__ lsum) {
    __shared__ __align__(16) float xl[64 * XLS];   // 65 KB, x tile; reused as w-gather
    __shared__ double disl[64][4];
    __shared__ int winner[64];
    __shared__ double ldis[64];
    int tid = threadIdx.x, bid = blockIdx.x;
    int b = bid >> 6, t0 = (bid & 63) << 6;
    int lane = tid & 63, wv = tid >> 6;

    // phase L: coalesced x tile load -> LDS (row-major [t][d], stride XLS)
#pragma unroll 4
    for (int pass = 0; pass < 16; ++pass) {
        int d = (tid >> 4) + (pass << 4);
        int t4 = (tid & 15) << 2;
        float4 v = *(const float4*)(x + ((size_t)b << 20) + ((size_t)d << 12) + t0 + t4);
        xl[(t4 + 0) * XLS + d] = v.x;
        xl[(t4 + 1) * XLS + d] = v.y;
        xl[(t4 + 2) * XLS + d] = v.z;
        xl[(t4 + 3) * XLS + d] = v.w;
    }
    __syncthreads();

    // phase R: fp64 distances; lanes: c = lane>>4 (candidate), dl = lane&15 (d chunk)
    int c = lane >> 4, dl = lane & 15;
    for (int rr = 0; rr < 16; ++rr) {
        int r = (wv << 4) + rr;
        int rowg = (b << 12) + t0 + r;
        unsigned ci = ((const unsigned*)cand)[((size_t)rowg << 2) + c] & 1023u;
        const float* wr = w + (ci << 8);
        double s = 0.0;
#pragma unroll
        for (int dd = 0; dd < 4; ++dd) {
            int d4 = (dd << 6) + (dl << 2);
            float4 xv = *(const float4*)(&xl[r * XLS + d4]);
            float4 wv4 = *(const float4*)(wr + d4);
            double e;
            e = (double)xv.x - (double)wv4.x; s = fma(e, e, s);
            e = (double)xv.y - (double)wv4.y; s = fma(e, e, s);
            e = (double)xv.z - (double)wv4.z; s = fma(e, e, s);
            e = (double)xv.w - (double)wv4.w; s = fma(e, e, s);
        }
#pragma unroll
        for (int m = 1; m <= 8; m <<= 1) s += __shfl_xor(s, m);
        if (dl == 0) disl[r][c] = s;
    }
    __syncthreads();

    // winner selection (tie -> smaller index)
    if (tid < 64) {
        int rowg = (b << 12) + t0 + tid;
        uint4 cc = cand[rowg];
        unsigned i0 = cc.x & 1023u, i1 = cc.y & 1023u, i2 = cc.z & 1023u, i3 = cc.w & 1023u;
        double dm = disl[tid][0]; unsigned ci = i0;
        double dk;
        dk = disl[tid][1]; if (dk < dm || (dk == dm && i1 < ci)) { dm = dk; ci = i1; }
        dk = disl[tid][2]; if (dk < dm || (dk == dm && i2 < ci)) { dm = dk; ci = i2; }
        dk = disl[tid][3]; if (dk < dm || (dk == dm && i3 < ci)) { dm = dk; ci = i3; }
        winner[tid] = (int)ci;
        ldis[tid] = dm;
        atomicAdd(&counts[ci], 1u);
    }
    __syncthreads();

    // gather winner w rows into LDS (reuse xl), one row per wave-instruction (coalesced 1KB)
    float* wg = xl;
#pragma unroll 4
    for (int rp = 0; rp < 16; ++rp) {
        int r = (rp << 2) + wv;
        int win = winner[r];
        *(float4*)(&wg[r * XLS + (lane << 2)]) =
            *(const float4*)(w + (win << 8) + (lane << 2));
    }
    __syncthreads();

    // emit: out[b][d][t0+t] = wg[t][d], coalesced float4 along t
    {
        int t4 = (tid & 15) << 2, dr = tid >> 4;
        float* ob = out + ((size_t)b << 20) + t0 + t4;
#pragma unroll 4
        for (int pass = 0; pass < 16; ++pass) {
            int d = dr + (pass << 4);
            float4 o;
            o.x = wg[(t4 + 0) * XLS + d];
            o.y = wg[(t4 + 1) * XLS + d];
            o.z = wg[(t4 + 2) * XLS + d];
            o.w = wg[(t4 + 3) * XLS + d];
            *(float4*)(ob + ((size_t)d << 12)) = o;
        }
    }

    // loss reduction
    __syncthreads();
    if (tid < 32) ldis[tid] += ldis[tid + 32];
    __syncthreads();
    if (tid < 16) ldis[tid] += ldis[tid + 16];
    __syncthreads();
    if (tid < 8) ldis[tid] += ldis[tid + 8];
    __syncthreads();
    if (tid < 4) ldis[tid] += ldis[tid + 4];
    __syncthreads();
    if (tid < 2) ldis[tid] += ldis[tid + 2];
    __syncthreads();
    if (tid == 0) atomicAdd(lsum, ldis[0] + ldis[1]);
}

// ---------------- finalize ----------------
__global__ void finalize(const unsigned* __restrict__ counts,
                         const double* __restrict__ lsum,
                         float* __restrict__ out2) {
    __shared__ double part[256];
    int tid = threadIdx.x;
    double s = 0.0;
    for (int i = tid; i < KK; i += 256) {
        double p = (double)counts[i] / (double)NROW;
        s += p * log(p + 1e-10);
    }
    part[tid] = s;
    __syncthreads();
    for (int st = 128; st > 0; st >>= 1) {
        if (tid < st) part[tid] += part[tid + st];
        __syncthreads();
    }
    if (tid == 0) {
        out2[0] = (float)(1.25 * (*lsum) / ((double)NROW * (double)DD));
        out2[1] = (float)exp(-part[0]);
    }
}

extern "C" void kernel_launch(void* const* d_in, const int* in_sizes, int n_in,
                              void* d_out, int out_size, void* d_ws, size_t ws_size,
                              hipStream_t stream) {
    const float* x = (const float*)d_in[0];
    const float* w = (const float*)d_in[1];
    float* out = (float*)d_out;
    char* ws = (char*)d_ws;
    _Float16* w16    = (_Float16*)ws;                         // 524288 B
    uint4*    cnd    = (uint4*)(ws + 524288);                 // 1 MB
    unsigned* counts = (unsigned*)(ws + 1572864);             // 4 KB
    float*    wsq    = (float*)(ws + 1576960);                // 4 KB
    double*   lsum   = (double*)(ws + 1581056);               // 8 B

    prep<<<128, 256, 0, stream>>>(w, w16, counts, lsum, wsq);
    stageA<<<512, 256, 0, stream>>>(x, w16, wsq, (uint4*)cnd);
    stageBC<<<1024, 256, 0, stream>>>(x, w, (const uint4*)cnd, out, counts, lsum);
    finalize<<<1, 256, 0, stream>>>(counts, lsum, out + (size_t)NROW * DD);
}